// Round 14
// baseline (191.416 us; speedup 1.0000x reference)
//
#include <hip/hip_runtime.h>
#include <hip/hip_bf16.h>

// MultiHeadAttention: B=2,S=1024,IN=512,P=4096,H=64,SZ=64
// cast -> transpose -> fused QKV GEMM (single-buffered; Q pre-scaled by SC2) ->
// flash attn (4-wave 32x32 MFMA, QBLK=128, Q-frags in regs, P entirely in
// registers via permlane32_swap -- no P LDS round-trip, ones-column rowsum) ->
// probsum (dbuf h-loop) -> split-K final GEMM. mask all-False -> ignored.
// MEASURED NOTES:
//  - GEMM dbuf (R5): 2x SLOWER (LDS halves occupancy). Single-buffer.
//  - probsum dbuf (R9): +40% (latency-bound regime, occupancy kept).
//  - attn K/V LDS-dbuf (R10): REGRESSED (lost a block).
//  - attn reg-prefetch K/V (R12): CATASTROPHIC spill (132us). gload_lds staging.
//  - attn bank conflicts (R9 3.1M / R11 6.4M / R13 7.4M): perf IDENTICAL ->
//    conflicts not binding; DS-OP COUNT is (LDS pipe ~74% busy). This round
//    removes 12/28 DS ops per thread-tile by keeping P in registers (T12).

typedef __bf16 bf16x8 __attribute__((ext_vector_type(8)));
typedef float f32x4 __attribute__((ext_vector_type(4)));
typedef float f32x16 __attribute__((ext_vector_type(16)));

#define DEV __device__ __forceinline__

// 0.125 * log2(e): softmax in base-2 (v_exp_f32 computes 2^x).
// Q projection is pre-scaled by this, so QK^T emits s' = s*SC2 directly.
#define SC2 0.18033688011112042f

DEV f32x4 mfma16(bf16x8 a, bf16x8 b, f32x4 c) {
  return __builtin_amdgcn_mfma_f32_16x16x32_bf16(a, b, c, 0, 0, 0);
}

DEV f32x16 mfma32(bf16x8 a, bf16x8 b, f32x16 c) {
  return __builtin_amdgcn_mfma_f32_32x32x16_bf16(a, b, c, 0, 0, 0);
}

DEV void gload_lds16(const void* g, void* l) {
  __builtin_amdgcn_global_load_lds(
      (const __attribute__((address_space(1))) unsigned int*)g,
      (__attribute__((address_space(3))) unsigned int*)l, 16, 0, 0);
}

DEV unsigned short bf16bits(float f) {
  __hip_bfloat16 h = __float2bfloat16(f);
  return *reinterpret_cast<unsigned short*>(&h);
}

DEV unsigned pkbf(float lo, float hi) {
  return (unsigned)bf16bits(lo) | ((unsigned)bf16bits(hi) << 16);
}

// Stage a 64x64 bf16 tile into LDS with T2 XOR swizzle (both-sides rule #21):
// logical element (r,k) lives at LDS elem r*64 + ((k/8)^(r&7))*8.
// 4-wave version (waves 0..3, 2 gloads each).
DEV void stage64(const __hip_bfloat16* src, size_t srcStride, __hip_bfloat16* dst,
                 int w, int lane) {
#pragma unroll
  for (int i = 0; i < 2; i++) {
    int r = i * 32 + w * 8 + (lane >> 3);
    int kg = (lane & 7) ^ (r & 7);
    gload_lds16(src + (size_t)r * srcStride + kg * 8, dst + (i * 32 + w * 8) * 64);
  }
}

// Stage a 32x64 tile (4 waves, 1 gload each).
DEV void stage32(const __hip_bfloat16* src, size_t srcStride, __hip_bfloat16* dst,
                 int w, int lane) {
  int r = w * 8 + (lane >> 3);
  int kg = (lane & 7) ^ (r & 7);
  gload_lds16(src + (size_t)r * srcStride + kg * 8, dst + (w * 8) * 64);
}

// Stage a 128x64 tile with 4 waves (4 gloads per thread).
DEV void stage128_4w(const __hip_bfloat16* src, size_t srcStride,
                     __hip_bfloat16* dst, int w, int lane) {
#pragma unroll
  for (int i = 0; i < 4; i++) {
    int r = i * 32 + w * 8 + (lane >> 3);
    int kg = (lane & 7) ^ (r & 7);
    gload_lds16(src + (size_t)r * srcStride + kg * 8, dst + (i * 32 + w * 8) * 64);
  }
}

// Read swizzled fragment: logical (row, kgroup kg) -> bf16x8 (16B-aligned).
DEV bf16x8 frag64(const __hip_bfloat16* tile, int row, int kg) {
  return *reinterpret_cast<const bf16x8*>(tile + row * 64 + ((kg ^ (row & 7)) * 8));
}

// ---------------- cast f32 -> bf16, all three tensors in one launch ----------------
__global__ void cast3_kernel(const float* __restrict__ q, const float* __restrict__ k,
                             const float* __restrict__ v, __hip_bfloat16* __restrict__ qb,
                             __hip_bfloat16* __restrict__ kb,
                             __hip_bfloat16* __restrict__ vb) {
  int i = blockIdx.x * blockDim.x + threadIdx.x;  // [0, 3*2^18)
  int which = i >> 18, off = i & 0x3FFFF;
  const float* src = which == 0 ? q : which == 1 ? k : v;
  __hip_bfloat16* dst = which == 0 ? qb : which == 1 ? kb : vb;
  float4 f = reinterpret_cast<const float4*>(src)[off];
  union { unsigned short u[4]; uint2 v2; } pk;
  pk.u[0] = bf16bits(f.x); pk.u[1] = bf16bits(f.y);
  pk.u[2] = bf16bits(f.z); pk.u[3] = bf16bits(f.w);
  reinterpret_cast<uint2*>(dst)[off] = pk.v2;
}

// ---------------- transpose + cast, all four weights in one launch ----------------
__global__ void transpose4(const float* __restrict__ Wq, const float* __restrict__ Wk,
                           const float* __restrict__ Wv, const float* __restrict__ Wf,
                           __hip_bfloat16* __restrict__ Wqt, __hip_bfloat16* __restrict__ Wkt,
                           __hip_bfloat16* __restrict__ Wvt, __hip_bfloat16* __restrict__ Wft) {
  __shared__ float t[32][33];
  const int z = blockIdx.z;
  const float* W = z == 0 ? Wq : z == 1 ? Wk : z == 2 ? Wv : Wf;
  __hip_bfloat16* Wt = z == 0 ? Wqt : z == 1 ? Wkt : z == 2 ? Wvt : Wft;
  int K, N, n0, k0;
  if (z < 3) { K = 512; N = 4096; n0 = blockIdx.x * 32; k0 = blockIdx.y * 32; }
  else       { K = 4096; N = 512; n0 = blockIdx.y * 32; k0 = blockIdx.x * 32; }
  int tx = threadIdx.x, ty = threadIdx.y;
#pragma unroll
  for (int i = 0; i < 4; i++)
    t[ty + i * 8][tx] = W[(size_t)(k0 + ty + i * 8) * N + n0 + tx];
  __syncthreads();
#pragma unroll
  for (int i = 0; i < 4; i++)
    Wt[(size_t)(n0 + ty + i * 8) * K + k0 + tx] = __float2bfloat16(t[tx][ty + i * 8]);
}

// ---------------- GEMM: C[M,N] = A[M,K] @ Bt[N,K]^T (+ bias) ----------------
// mode 0: bf16 natural, value = (acc+bias)*scale
// mode 1: bf16 transposed per batch (Vt[b][n][s]), value = acc+bias
// mode 3: f32 partial (split-K chunk blockIdx.z), no bias
struct GemmArgs {
  const __hip_bfloat16* A;
  const __hip_bfloat16* Bt;
  const float* bias;
  void* C;
  int mode;
  float scale;
};

template <int MI, int NI, int SPLITK>
__global__ __launch_bounds__(256, 2) void gemm_bf16(GemmArgs g0, GemmArgs g1,
                                                    GemmArgs g2, int Ndim, int Kdim) {
  const GemmArgs& g =
      (SPLITK > 1) ? g0 : (blockIdx.z == 0 ? g0 : blockIdx.z == 1 ? g1 : g2);
  constexpr int BM = 32 * MI, BN = 32 * NI;
  __shared__ __hip_bfloat16 As[BM * 64];
  __shared__ __hip_bfloat16 Bs[BN * 64];
  const int tid = threadIdx.x;
  const int lane = tid & 63, w = tid >> 6;
  const int wr = w >> 1, wc = w & 1;
  const int row0 = blockIdx.y * BM, col0 = blockIdx.x * BN;
  const int l15 = lane & 15, l16 = lane >> 4;

  const int kchunk = Kdim / SPLITK;
  const int kbeg = (SPLITK > 1) ? blockIdx.z * kchunk : 0;

  f32x4 acc[MI][NI] = {};

  const int sr8 = w * 8 + (lane >> 3);
  const int sslot = lane & 7;

  for (int t = 0; t < kchunk / 64; ++t) {
    const int k0 = kbeg + t * 64;
    __syncthreads();
#pragma unroll
    for (int i = 0; i < MI; i++) {
      int r = i * 32 + sr8;
      int kg = sslot ^ (r & 7);
      gload_lds16(g.A + (size_t)(row0 + r) * Kdim + k0 + kg * 8,
                  As + (i * 32 + w * 8) * 64);
    }
#pragma unroll
    for (int i = 0; i < NI; i++) {
      int r = i * 32 + sr8;
      int kg = sslot ^ (r & 7);
      gload_lds16(g.Bt + (size_t)(col0 + r) * Kdim + k0 + kg * 8,
                  Bs + (i * 32 + w * 8) * 64);
    }
    asm volatile("s_waitcnt vmcnt(0)" ::: "memory");
    __syncthreads();
#pragma unroll
    for (int ks = 0; ks < 2; ks++) {
      const int kg = ks * 4 + l16;
      bf16x8 af[MI], bfr[NI];
#pragma unroll
      for (int mi = 0; mi < MI; mi++)
        af[mi] = frag64(As, wr * (16 * MI) + mi * 16 + l15, kg);
#pragma unroll
      for (int ni = 0; ni < NI; ni++)
        bfr[ni] = frag64(Bs, wc * (16 * NI) + ni * 16 + l15, kg);
      __builtin_amdgcn_s_setprio(1);
#pragma unroll
      for (int mi = 0; mi < MI; mi++)
#pragma unroll
        for (int ni = 0; ni < NI; ni++)
          acc[mi][ni] = mfma16(af[mi], bfr[ni], acc[mi][ni]);
      __builtin_amdgcn_s_setprio(0);
    }
  }

#pragma unroll
  for (int mi = 0; mi < MI; mi++) {
    const int rbase = row0 + wr * (16 * MI) + mi * 16 + l16 * 4;
#pragma unroll
    for (int ni = 0; ni < NI; ni++) {
      const int col = col0 + wc * (16 * NI) + ni * 16 + l15;
      if (g.mode == 0) {
        const float bv = g.bias[col];
#pragma unroll
        for (int rg = 0; rg < 4; rg++)
          ((__hip_bfloat16*)g.C)[(size_t)(rbase + rg) * Ndim + col] =
              __float2bfloat16((acc[mi][ni][rg] + bv) * g.scale);
      } else if (g.mode == 1) {
        const float bv = g.bias[col];
        const int b = rbase >> 10, s = rbase & 1023;
        union { unsigned short u[4]; uint2 v2; } pk;
#pragma unroll
        for (int rg = 0; rg < 4; rg++) pk.u[rg] = bf16bits(acc[mi][ni][rg] + bv);
        *reinterpret_cast<uint2*>((__hip_bfloat16*)g.C +
                                  ((size_t)b * 4096 + col) * 1024 + s) = pk.v2;
      } else {  // mode 3: split-K f32 partial, no bias
        float* base = (float*)g.C +
                      (size_t)blockIdx.z * (size_t)(gridDim.y * BM) * Ndim;
#pragma unroll
        for (int rg = 0; rg < 4; rg++)
          base[(size_t)(rbase + rg) * Ndim + col] = acc[mi][ni][rg];
      }
    }
  }
}

// ---------------- split-K reduce: out = sum_z partial[z] + bias ----------------
__global__ void reduce4_bias(const float* __restrict__ part,
                             const float* __restrict__ bias,
                             float* __restrict__ out) {
  int i = blockIdx.x * blockDim.x + threadIdx.x;  // 262144 float4 groups
  const size_t S4 = (size_t)2048 * 512 / 4;
  float4 a = reinterpret_cast<const float4*>(part)[i];
  float4 b = reinterpret_cast<const float4*>(part)[i + S4];
  float4 c = reinterpret_cast<const float4*>(part)[i + 2 * S4];
  float4 d = reinterpret_cast<const float4*>(part)[i + 3 * S4];
  float4 bv = reinterpret_cast<const float4*>(bias)[i & 127];
  float4 r;
  r.x = a.x + b.x + c.x + d.x + bv.x;
  r.y = a.y + b.y + c.y + d.y + bv.y;
  r.z = a.z + b.z + c.z + d.z + bv.z;
  r.w = a.w + b.w + c.w + d.w + bv.w;
  reinterpret_cast<float4*>(out)[i] = r;
}

// ---------------- flash attention, 4-wave 32x32 MFMA, QBLK=128, reg-P ----------------
// Qp pre-scaled by SC2 -> QK^T yields s', P = 2^s'.
// Swapped QK^T: mfma32(A=K, B=Q) -> C[k][q]: lane(l31,hi') owns q=l31,
// k = kb*32 + 8g + 4hi' + j (g=reg>>2, j=reg&3).
// PV A-fragment needs lane(l31,hi): P[q=l31][k = c*16 + 8hi + j], j=0..7.
// Register hand-off: for (kb,hc): item(g=2hc) covers k-in-32 = hc*16+[0,4)+4hi';
// item(g=2hc+1) covers hc*16+8+[0,4)+4hi'. One v_permlane32_swap_b32 per
// u32-pair (A=item(2hc), B=item(2hc+1)) gives:
//   lower lanes: A'={own hi'=0}, B'={A from upper = hi'=1}  -> k hc*16+[0,8)
//   upper lanes: A'={B lower = g+1,hi'=0}, B'={own g+1,hi'=1} -> k hc*16+8+[0,8)
// frag(c=kb*2+hc) = [Au0',Au1',Bu0',Bu1'] -- exactly the A-layout. No P LDS.
__global__ __launch_bounds__(256, 4) void attn_flash(
    const __hip_bfloat16* __restrict__ Qp, const __hip_bfloat16* __restrict__ Kp,
    const __hip_bfloat16* __restrict__ Vt, __hip_bfloat16* __restrict__ ctx,
    float* __restrict__ lden) {
  const int lin = blockIdx.x;                   // 1024 blocks
  const int nw = (lin & 7) * 128 + (lin >> 3);  // XCD-chunked: 8 consecutive = same bh
  const int bh = nw >> 3, q0 = (nw & 7) * 128;
  const int b = bh >> 6, h = bh & 63;
  // smem: [0,8192): Qs 128x64; [8192,12288): Ks 64x64; [12288,16384): Vs 64x64.
  __shared__ __hip_bfloat16 smem[16384];
  __hip_bfloat16* Qs = smem;
  __hip_bfloat16* Ks = smem + 8192;
  __hip_bfloat16* Vs = smem + 12288;
  const int tid = threadIdx.x, lane = tid & 63, w = tid >> 6;  // w 0..3
  const int l31 = lane & 31, hi = lane >> 5;

  const __hip_bfloat16* Qg = Qp + ((size_t)b * 1024 + q0) * 4096 + h * 64;
  const __hip_bfloat16* Kg = Kp + (size_t)b * 1024 * 4096 + h * 64;
  const __hip_bfloat16* Vg = Vt + ((size_t)b * 4096 + h * 64) * 1024;

  stage128_4w(Qg, 4096, Qs, w, lane);
  asm volatile("s_waitcnt vmcnt(0)" ::: "memory");
  __syncthreads();

  // Hoist this wave's Q fragments (B-operand: col q = l31, d-chunk c).
  bf16x8 qf[4];
#pragma unroll
  for (int c = 0; c < 4; c++)
    qf[c] = frag64(Qs, w * 32 + l31, c * 2 + hi);

  bf16x8 kones;
#pragma unroll
  for (int j = 0; j < 8; j++) kones[j] = (__bf16)1.0f;

  f32x16 o0 = {}, o1 = {}, o4 = {};

  for (int kt = 0; kt < 16; kt++) {
    __syncthreads();  // prev-tile K/V reads done (and Q-hoists on first iter)
    stage64(Kg + (size_t)(kt * 64) * 4096, 4096, Ks, w, lane);
    stage64(Vg + kt * 64, 1024, Vs, w, lane);
    asm volatile("s_waitcnt vmcnt(0)" ::: "memory");
    __syncthreads();

    // QK^T + in-register P formation (exp2 -> cvt_pk -> permlane32_swap).
    bf16x8 pf0, pf1, pf2, pf3;
#pragma unroll
    for (int kb = 0; kb < 2; kb++) {
      f32x16 sc = {};
      __builtin_amdgcn_s_setprio(1);
#pragma unroll
      for (int c = 0; c < 4; c++)
        sc = mfma32(frag64(Ks, kb * 32 + l31, c * 2 + hi), qf[c], sc);
      __builtin_amdgcn_s_setprio(0);
#pragma unroll
      for (int hc = 0; hc < 2; hc++) {
        unsigned au0 = pkbf(exp2f(sc[8 * hc + 0]), exp2f(sc[8 * hc + 1]));
        unsigned au1 = pkbf(exp2f(sc[8 * hc + 2]), exp2f(sc[8 * hc + 3]));
        unsigned bu0 = pkbf(exp2f(sc[8 * hc + 4]), exp2f(sc[8 * hc + 5]));
        unsigned bu1 = pkbf(exp2f(sc[8 * hc + 6]), exp2f(sc[8 * hc + 7]));
        asm volatile("v_permlane32_swap_b32 %0, %1" : "+v"(au0), "+v"(bu0));
        asm volatile("v_permlane32_swap_b32 %0, %1" : "+v"(au1), "+v"(bu1));
        union { unsigned u[4]; bf16x8 v; } f;
        f.u[0] = au0; f.u[1] = au1; f.u[2] = bu0; f.u[3] = bu1;
        if (kb == 0) { if (hc == 0) pf0 = f.v; else pf1 = f.v; }
        else         { if (hc == 0) pf2 = f.v; else pf3 = f.v; }
      }
    }

    // PV + rowsum: A = P (regs), B = V^T (col d = l31) / ones.
    __builtin_amdgcn_s_setprio(1);
    o0 = mfma32(pf0, frag64(Vs, l31, 0 * 2 + hi), o0);
    o1 = mfma32(pf0, frag64(Vs, 32 + l31, 0 * 2 + hi), o1);
    o4 = mfma32(pf0, kones, o4);
    o0 = mfma32(pf1, frag64(Vs, l31, 1 * 2 + hi), o0);
    o1 = mfma32(pf1, frag64(Vs, 32 + l31, 1 * 2 + hi), o1);
    o4 = mfma32(pf1, kones, o4);
    o0 = mfma32(pf2, frag64(Vs, l31, 2 * 2 + hi), o0);
    o1 = mfma32(pf2, frag64(Vs, 32 + l31, 2 * 2 + hi), o1);
    o4 = mfma32(pf2, kones, o4);
    o0 = mfma32(pf3, frag64(Vs, l31, 3 * 2 + hi), o0);
    o1 = mfma32(pf3, frag64(Vs, 32 + l31, 3 * 2 + hi), o1);
    o4 = mfma32(pf3, kones, o4);
    __builtin_amdgcn_s_setprio(0);
  }

  // Epilogue: C[q][d] rows q=(reg&3)+8*(reg>>2)+4*hi (+w*32), col d=l31(+32).
#pragma unroll
  for (int reg = 0; reg < 16; reg++) {
    const int qr = (reg & 3) + 8 * (reg >> 2) + 4 * hi;
    const float invl = 1.f / o4[reg];
    const size_t rowoff =
        ((size_t)b * 1024 + q0 + w * 32 + qr) * 4096 + h * 64;
    ctx[rowoff + l31] = __float2bfloat16(o0[reg] * invl);
    ctx[rowoff + 32 + l31] = __float2bfloat16(o1[reg] * invl);
    if (l31 == 0)
      lden[(size_t)bh * 1024 + q0 + w * 32 + qr] = log2f(o4[reg]);
  }
}

// ---------------- probsum: attn_sum[b,q,k] = sum_h 2^(s' - lden_h) ----------------
// k-tile 32, 1024 blocks; 2-phase double-buffered h-loop (stage h+1 before
// compute h). LDS 40KB -> 4 blocks/CU. exp-fold: lden subtracted inside exp2.
__global__ __launch_bounds__(256, 4) void probsum(
    const __hip_bfloat16* __restrict__ Qp, const __hip_bfloat16* __restrict__ Kp,
    const float* __restrict__ lden, float* __restrict__ outA) {
  const int lin = blockIdx.x;
  const int nw = (lin & 7) * 128 + (lin >> 3);  // XCD-chunked
  const int k0 = (nw & 31) * 32, q0 = ((nw >> 5) & 15) * 64, b = nw >> 9;
  __shared__ __hip_bfloat16 Qs[2][64 * 64];
  __shared__ __hip_bfloat16 Ks[2][32 * 64];
  __shared__ float Ls[64 * 64];  // [h][q]
  const int tid = threadIdx.x, lane = tid & 63, w = tid >> 6;
  const int l15 = lane & 15, l16 = lane >> 4;

  for (int i = tid; i < 4096; i += 256) {
    int h = i >> 6, qq = i & 63;
    Ls[h * 64 + qq] = lden[(size_t)(b * 64 + h) * 1024 + q0 + qq];
  }

  auto STG = [&](int buf, int h) {
    stage64(Qp + ((size_t)b * 1024 + q0) * 4096 + h * 64, 4096, Qs[buf], w, lane);
    stage32(Kp + ((size_t)b * 1024 + k0) * 4096 + h * 64, 4096, Ks[buf], w, lane);
  };

  f32x4 acc[2] = {};
  const int qrow = w * 16 + l16 * 4;

  STG(0, 0);
  asm volatile("s_waitcnt vmcnt(0)" ::: "memory");
  __syncthreads();
  int cur = 0;
  for (int h = 0; h < 64; h++) {
    if (h + 1 < 64) STG(cur ^ 1, h + 1);
    f32x4 sc[2] = {};
    __builtin_amdgcn_s_setprio(1);
#pragma unroll
    for (int ks = 0; ks < 2; ks++) {
      const int kg = ks * 4 + l16;
      bf16x8 aq = frag64(Qs[cur], w * 16 + l15, kg);
#pragma unroll
      for (int ni = 0; ni < 2; ni++)
        sc[ni] = mfma16(aq, frag64(Ks[cur], ni * 16 + l15, kg), sc[ni]);
    }
    __builtin_amdgcn_s_setprio(0);
    float nl[4];
#pragma unroll
    for (int rg = 0; rg < 4; rg++) nl[rg] = Ls[h * 64 + qrow + rg];
#pragma unroll
    for (int ni = 0; ni < 2; ni++)
#pragma unroll
      for (int rg = 0; rg < 4; rg++)
        acc[ni][rg] += exp2f(sc[ni][rg] - nl[rg]);
    asm volatile("s_waitcnt vmcnt(0)" ::: "memory");
    __syncthreads();
    cur ^= 1;
  }
  float* og = outA + ((size_t)b * 1024 + q0 + qrow) * 1024 + k0;
#pragma unroll
  for (int ni = 0; ni < 2; ni++)
#pragma unroll
    for (int rg = 0; rg < 4; rg++)
      og[(size_t)rg * 1024 + ni * 16 + l15] = acc[ni][rg];
}

// ---------------- host ----------------
extern "C" void kernel_launch(void* const* d_in, const int* in_sizes, int n_in,
                              void* d_out, int out_size, void* d_ws, size_t ws_size,
                              hipStream_t stream) {
  const float* q = (const float*)d_in[0];
  const float* k = (const float*)d_in[1];
  const float* v = (const float*)d_in[2];
  const float* Wq = (const float*)d_in[4];
  const float* bq = (const float*)d_in[5];
  const float* Wk = (const float*)d_in[6];
  const float* bk = (const float*)d_in[7];
  const float* Wv = (const float*)d_in[8];
  const float* bv = (const float*)d_in[9];
  const float* Wf = (const float*)d_in[10];
  const float* bfv = (const float*)d_in[11];
  float* out = (float*)d_out;
  float* attn_sum = out + (size_t)2048 * 512;

  char* ws = (char*)d_ws;
  auto alloc = [&](size_t bytes) {
    char* p = ws;
    ws += (bytes + 255) & ~(size_t)255;
    return p;
  };
  __hip_bfloat16* qb = (__hip_bfloat16*)alloc((size_t)2048 * 512 * 2);
  __hip_bfloat16* kb = (__hip_bfloat16*)alloc((size_t)2048 * 512 * 2);
  __hip_bfloat16* vb = (__hip_bfloat16*)alloc((size_t)2048 * 512 * 2);
  __hip_bfloat16* Wqt = (__hip_bfloat16*)alloc((size_t)4096 * 512 * 2);
  __hip_bfloat16* Wkt = (__hip_bfloat16*)alloc((size_t)4096 * 512 * 2);
  __hip_bfloat16* Wvt = (__hip_bfloat16*)alloc((size_t)4096 * 512 * 2);
  __hip_bfloat16* Wft = (__hip_bfloat16*)alloc((size_t)512 * 4096 * 2);
  __hip_bfloat16* Qp = (__hip_bfloat16*)alloc((size_t)2048 * 4096 * 2);
  __hip_bfloat16* Kp = (__hip_bfloat16*)alloc((size_t)2048 * 4096 * 2);
  __hip_bfloat16* Vt = (__hip_bfloat16*)alloc((size_t)2048 * 4096 * 2);
  __hip_bfloat16* ctx = (__hip_bfloat16*)alloc((size_t)2048 * 4096 * 2);
  float* lden = (float*)alloc((size_t)128 * 1024 * 4);
  // Split-K partials (4 x 2048 x 512 f32 = 16.8MB) reuse the dead qb..Wvt
  // region (18.9MB, all dead after the QKV GEMM).
  float* partial = (float*)qb;

  cast3_kernel<<<3072, 256, 0, stream>>>(q, k, v, qb, kb, vb);
  transpose4<<<dim3(128, 16, 4), dim3(32, 8), 0, stream>>>(Wq, Wk, Wv, Wf, Wqt, Wkt,
                                                           Wvt, Wft);
  GemmArgs gq{qb, Wqt, bq, Qp, 0, SC2};   // Q pre-scaled by SC2
  GemmArgs gk{kb, Wkt, bk, Kp, 0, 1.0f};
  GemmArgs gv{vb, Wvt, bv, Vt, 1, 1.0f};
  gemm_bf16<4, 4, 1><<<dim3(32, 16, 3), 256, 0, stream>>>(gq, gk, gv, 4096, 512);

  attn_flash<<<1024, 256, 0, stream>>>(Qp, Kp, Vt, ctx, lden);
  probsum<<<1024, 256, 0, stream>>>(Qp, Kp, lden, attn_sum);

  GemmArgs gf{ctx, Wft, bfv, partial, 3, 1.0f};
  gemm_bf16<2, 2, 4><<<dim3(8, 32, 4), 256, 0, stream>>>(gf, gf, gf, 512, 4096);
  reduce4_bias<<<1024, 256, 0, stream>>>(partial, bfv, out);
}

// Round 16
// 190.598 us; speedup vs baseline: 1.0043x; 1.0043x over previous
//
#include <hip/hip_runtime.h>
#include <hip/hip_bf16.h>

// MultiHeadAttention: B=2,S=1024,IN=512,P=4096,H=64,SZ=64
// cast -> transpose -> fused QKV GEMM (single-buffered; Q pre-scaled by SC2) ->
// flash attn (4-wave 32x32 MFMA, QBLK=128, KVBLK=128: 8 serial stage round-trips
// instead of 16, Q-frags in regs, P in registers via permlane32_swap, K tile in
// dead-Q region, ones-column rowsum) -> probsum (dbuf h-loop) -> split-K final
// GEMM. mask all-False -> ignored.
// MEASURED NOTES:
//  - GEMM dbuf (R5): 2x SLOWER (LDS halves occupancy). Single-buffer.
//  - probsum dbuf (R9): +40% (latency-bound regime, occupancy kept).
//  - attn K/V LDS-dbuf (R10): REGRESSED (lost a block).
//  - attn reg-prefetch (R12): catastrophic spill. attn dbuf-in-deadQ (R15):
//    RACE (absmax 4e-2) -- and __syncthreads drains vmcnt anyway, so
//    cross-barrier prefetch is structurally void. DO NOT RETRY.
//  - attn R9/R11/R14 all ~69us across 3 structures; model: 16 serial
//    {barrier+stage+drain+compute} round-trips ~ 167k cyc. This round halves
//    the round-trip count with KVBLK=128 on the PROVEN R14 sync skeleton.

typedef __bf16 bf16x8 __attribute__((ext_vector_type(8)));
typedef float f32x4 __attribute__((ext_vector_type(4)));
typedef float f32x16 __attribute__((ext_vector_type(16)));

#define DEV __device__ __forceinline__

// 0.125 * log2(e): softmax in base-2 (v_exp_f32 computes 2^x).
// Q projection is pre-scaled by this, so QK^T emits s' = s*SC2 directly.
#define SC2 0.18033688011112042f

DEV f32x4 mfma16(bf16x8 a, bf16x8 b, f32x4 c) {
  return __builtin_amdgcn_mfma_f32_16x16x32_bf16(a, b, c, 0, 0, 0);
}

DEV f32x16 mfma32(bf16x8 a, bf16x8 b, f32x16 c) {
  return __builtin_amdgcn_mfma_f32_32x32x16_bf16(a, b, c, 0, 0, 0);
}

DEV void gload_lds16(const void* g, void* l) {
  __builtin_amdgcn_global_load_lds(
      (const __attribute__((address_space(1))) unsigned int*)g,
      (__attribute__((address_space(3))) unsigned int*)l, 16, 0, 0);
}

DEV unsigned short bf16bits(float f) {
  __hip_bfloat16 h = __float2bfloat16(f);
  return *reinterpret_cast<unsigned short*>(&h);
}

DEV unsigned pkbf(float lo, float hi) {
  return (unsigned)bf16bits(lo) | ((unsigned)bf16bits(hi) << 16);
}

// Stage a 64x64 bf16 tile into LDS with T2 XOR swizzle (both-sides rule #21):
// logical element (r,k) lives at LDS elem r*64 + ((k/8)^(r&7))*8.
// 4-wave version (waves 0..3, 2 gloads each).
DEV void stage64(const __hip_bfloat16* src, size_t srcStride, __hip_bfloat16* dst,
                 int w, int lane) {
#pragma unroll
  for (int i = 0; i < 2; i++) {
    int r = i * 32 + w * 8 + (lane >> 3);
    int kg = (lane & 7) ^ (r & 7);
    gload_lds16(src + (size_t)r * srcStride + kg * 8, dst + (i * 32 + w * 8) * 64);
  }
}

// Stage a 32x64 tile (4 waves, 1 gload each).
DEV void stage32(const __hip_bfloat16* src, size_t srcStride, __hip_bfloat16* dst,
                 int w, int lane) {
  int r = w * 8 + (lane >> 3);
  int kg = (lane & 7) ^ (r & 7);
  gload_lds16(src + (size_t)r * srcStride + kg * 8, dst + (w * 8) * 64);
}

// Stage a 128x64 tile with 4 waves (4 gloads per thread).
DEV void stage128_4w(const __hip_bfloat16* src, size_t srcStride,
                     __hip_bfloat16* dst, int w, int lane) {
#pragma unroll
  for (int i = 0; i < 4; i++) {
    int r = i * 32 + w * 8 + (lane >> 3);
    int kg = (lane & 7) ^ (r & 7);
    gload_lds16(src + (size_t)r * srcStride + kg * 8, dst + (i * 32 + w * 8) * 64);
  }
}

// Read swizzled fragment: logical (row, kgroup kg) -> bf16x8 (16B-aligned).
DEV bf16x8 frag64(const __hip_bfloat16* tile, int row, int kg) {
  return *reinterpret_cast<const bf16x8*>(tile + row * 64 + ((kg ^ (row & 7)) * 8));
}

// ---------------- cast f32 -> bf16, all three tensors in one launch ----------------
__global__ void cast3_kernel(const float* __restrict__ q, const float* __restrict__ k,
                             const float* __restrict__ v, __hip_bfloat16* __restrict__ qb,
                             __hip_bfloat16* __restrict__ kb,
                             __hip_bfloat16* __restrict__ vb) {
  int i = blockIdx.x * blockDim.x + threadIdx.x;  // [0, 3*2^18)
  int which = i >> 18, off = i & 0x3FFFF;
  const float* src = which == 0 ? q : which == 1 ? k : v;
  __hip_bfloat16* dst = which == 0 ? qb : which == 1 ? kb : vb;
  float4 f = reinterpret_cast<const float4*>(src)[off];
  union { unsigned short u[4]; uint2 v2; } pk;
  pk.u[0] = bf16bits(f.x); pk.u[1] = bf16bits(f.y);
  pk.u[2] = bf16bits(f.z); pk.u[3] = bf16bits(f.w);
  reinterpret_cast<uint2*>(dst)[off] = pk.v2;
}

// ---------------- transpose + cast, all four weights in one launch ----------------
__global__ void transpose4(const float* __restrict__ Wq, const float* __restrict__ Wk,
                           const float* __restrict__ Wv, const float* __restrict__ Wf,
                           __hip_bfloat16* __restrict__ Wqt, __hip_bfloat16* __restrict__ Wkt,
                           __hip_bfloat16* __restrict__ Wvt, __hip_bfloat16* __restrict__ Wft) {
  __shared__ float t[32][33];
  const int z = blockIdx.z;
  const float* W = z == 0 ? Wq : z == 1 ? Wk : z == 2 ? Wv : Wf;
  __hip_bfloat16* Wt = z == 0 ? Wqt : z == 1 ? Wkt : z == 2 ? Wvt : Wft;
  int K, N, n0, k0;
  if (z < 3) { K = 512; N = 4096; n0 = blockIdx.x * 32; k0 = blockIdx.y * 32; }
  else       { K = 4096; N = 512; n0 = blockIdx.y * 32; k0 = blockIdx.x * 32; }
  int tx = threadIdx.x, ty = threadIdx.y;
#pragma unroll
  for (int i = 0; i < 4; i++)
    t[ty + i * 8][tx] = W[(size_t)(k0 + ty + i * 8) * N + n0 + tx];
  __syncthreads();
#pragma unroll
  for (int i = 0; i < 4; i++)
    Wt[(size_t)(n0 + ty + i * 8) * K + k0 + tx] = __float2bfloat16(t[tx][ty + i * 8]);
}

// ---------------- GEMM: C[M,N] = A[M,K] @ Bt[N,K]^T (+ bias) ----------------
// mode 0: bf16 natural, value = (acc+bias)*scale
// mode 1: bf16 transposed per batch (Vt[b][n][s]), value = acc+bias
// mode 3: f32 partial (split-K chunk blockIdx.z), no bias
struct GemmArgs {
  const __hip_bfloat16* A;
  const __hip_bfloat16* Bt;
  const float* bias;
  void* C;
  int mode;
  float scale;
};

template <int MI, int NI, int SPLITK>
__global__ __launch_bounds__(256, 2) void gemm_bf16(GemmArgs g0, GemmArgs g1,
                                                    GemmArgs g2, int Ndim, int Kdim) {
  const GemmArgs& g =
      (SPLITK > 1) ? g0 : (blockIdx.z == 0 ? g0 : blockIdx.z == 1 ? g1 : g2);
  constexpr int BM = 32 * MI, BN = 32 * NI;
  __shared__ __hip_bfloat16 As[BM * 64];
  __shared__ __hip_bfloat16 Bs[BN * 64];
  const int tid = threadIdx.x;
  const int lane = tid & 63, w = tid >> 6;
  const int wr = w >> 1, wc = w & 1;
  const int row0 = blockIdx.y * BM, col0 = blockIdx.x * BN;
  const int l15 = lane & 15, l16 = lane >> 4;

  const int kchunk = Kdim / SPLITK;
  const int kbeg = (SPLITK > 1) ? blockIdx.z * kchunk : 0;

  f32x4 acc[MI][NI] = {};

  const int sr8 = w * 8 + (lane >> 3);
  const int sslot = lane & 7;

  for (int t = 0; t < kchunk / 64; ++t) {
    const int k0 = kbeg + t * 64;
    __syncthreads();
#pragma unroll
    for (int i = 0; i < MI; i++) {
      int r = i * 32 + sr8;
      int kg = sslot ^ (r & 7);
      gload_lds16(g.A + (size_t)(row0 + r) * Kdim + k0 + kg * 8,
                  As + (i * 32 + w * 8) * 64);
    }
#pragma unroll
    for (int i = 0; i < NI; i++) {
      int r = i * 32 + sr8;
      int kg = sslot ^ (r & 7);
      gload_lds16(g.Bt + (size_t)(col0 + r) * Kdim + k0 + kg * 8,
                  Bs + (i * 32 + w * 8) * 64);
    }
    asm volatile("s_waitcnt vmcnt(0)" ::: "memory");
    __syncthreads();
#pragma unroll
    for (int ks = 0; ks < 2; ks++) {
      const int kg = ks * 4 + l16;
      bf16x8 af[MI], bfr[NI];
#pragma unroll
      for (int mi = 0; mi < MI; mi++)
        af[mi] = frag64(As, wr * (16 * MI) + mi * 16 + l15, kg);
#pragma unroll
      for (int ni = 0; ni < NI; ni++)
        bfr[ni] = frag64(Bs, wc * (16 * NI) + ni * 16 + l15, kg);
      __builtin_amdgcn_s_setprio(1);
#pragma unroll
      for (int mi = 0; mi < MI; mi++)
#pragma unroll
        for (int ni = 0; ni < NI; ni++)
          acc[mi][ni] = mfma16(af[mi], bfr[ni], acc[mi][ni]);
      __builtin_amdgcn_s_setprio(0);
    }
  }

#pragma unroll
  for (int mi = 0; mi < MI; mi++) {
    const int rbase = row0 + wr * (16 * MI) + mi * 16 + l16 * 4;
#pragma unroll
    for (int ni = 0; ni < NI; ni++) {
      const int col = col0 + wc * (16 * NI) + ni * 16 + l15;
      if (g.mode == 0) {
        const float bv = g.bias[col];
#pragma unroll
        for (int rg = 0; rg < 4; rg++)
          ((__hip_bfloat16*)g.C)[(size_t)(rbase + rg) * Ndim + col] =
              __float2bfloat16((acc[mi][ni][rg] + bv) * g.scale);
      } else if (g.mode == 1) {
        const float bv = g.bias[col];
        const int b = rbase >> 10, s = rbase & 1023;
        union { unsigned short u[4]; uint2 v2; } pk;
#pragma unroll
        for (int rg = 0; rg < 4; rg++) pk.u[rg] = bf16bits(acc[mi][ni][rg] + bv);
        *reinterpret_cast<uint2*>((__hip_bfloat16*)g.C +
                                  ((size_t)b * 4096 + col) * 1024 + s) = pk.v2;
      } else {  // mode 3: split-K f32 partial, no bias
        float* base = (float*)g.C +
                      (size_t)blockIdx.z * (size_t)(gridDim.y * BM) * Ndim;
#pragma unroll
        for (int rg = 0; rg < 4; rg++)
          base[(size_t)(rbase + rg) * Ndim + col] = acc[mi][ni][rg];
      }
    }
  }
}

// ---------------- split-K reduce: out = sum_z partial[z] + bias ----------------
__global__ void reduce4_bias(const float* __restrict__ part,
                             const float* __restrict__ bias,
                             float* __restrict__ out) {
  int i = blockIdx.x * blockDim.x + threadIdx.x;  // 262144 float4 groups
  const size_t S4 = (size_t)2048 * 512 / 4;
  float4 a = reinterpret_cast<const float4*>(part)[i];
  float4 b = reinterpret_cast<const float4*>(part)[i + S4];
  float4 c = reinterpret_cast<const float4*>(part)[i + 2 * S4];
  float4 d = reinterpret_cast<const float4*>(part)[i + 3 * S4];
  float4 bv = reinterpret_cast<const float4*>(bias)[i & 127];
  float4 r;
  r.x = a.x + b.x + c.x + d.x + bv.x;
  r.y = a.y + b.y + c.y + d.y + bv.y;
  r.z = a.z + b.z + c.z + d.z + bv.z;
  r.w = a.w + b.w + c.w + d.w + bv.w;
  reinterpret_cast<float4*>(out)[i] = r;
}

// ---------------- flash attention: 4-wave 32x32, reg-P, KVBLK=128 ----------------
// Qp pre-scaled by SC2 -> QK^T yields s', P = 2^s'.
// Swapped QK^T: mfma32(A=K, B=Q) -> C[k][q]; in-register P via exp2 -> cvt_pk
// -> v_permlane32_swap (layout verified R14). Per 128-key tile: 4 sub-tiles of
// 32 keys; K tile (128x64) as two 64x64 blocks in the dead-Q region; V tile
// (64d x 128s) as two 64x64 s-halves. R14's proven sync skeleton:
// {barrier; stage; vmcnt(0); barrier; compute} x 8 (was x 16).
// LDS 32KB -> 4 blocks/CU, occupancy unchanged.
__global__ __launch_bounds__(256, 4) void attn_flash(
    const __hip_bfloat16* __restrict__ Qp, const __hip_bfloat16* __restrict__ Kp,
    const __hip_bfloat16* __restrict__ Vt, __hip_bfloat16* __restrict__ ctx,
    float* __restrict__ lden) {
  const int lin = blockIdx.x;                   // 1024 blocks
  const int nw = (lin & 7) * 128 + (lin >> 3);  // XCD-chunked: 8 consecutive = same bh
  const int bh = nw >> 3, q0 = (nw & 7) * 128;
  const int b = bh >> 6, h = bh & 63;
  // smem: [0,4096) KsLo, [4096,8192) KsHi  (= Q region during prologue);
  //       [8192,12288) VsLo, [12288,16384) VsHi.  Total 32KB.
  __shared__ __hip_bfloat16 smem[16384];
  __hip_bfloat16* KsLo = smem;
  __hip_bfloat16* KsHi = smem + 4096;
  __hip_bfloat16* VsLo = smem + 8192;
  __hip_bfloat16* VsHi = smem + 12288;
  const int tid = threadIdx.x, lane = tid & 63, w = tid >> 6;  // w 0..3
  const int l31 = lane & 31, hi = lane >> 5;

  const __hip_bfloat16* Qg = Qp + ((size_t)b * 1024 + q0) * 4096 + h * 64;
  const __hip_bfloat16* Kg = Kp + (size_t)b * 1024 * 4096 + h * 64;
  const __hip_bfloat16* Vg = Vt + ((size_t)b * 4096 + h * 64) * 1024;

  // Prologue: stage Q into [0,8192), drain, hoist to regs. The loop-top
  // barrier (kt=0) separates the hoist ds_reads from the K-stage overwrite.
  stage128_4w(Qg, 4096, smem, w, lane);
  asm volatile("s_waitcnt vmcnt(0)" ::: "memory");
  __syncthreads();

  bf16x8 qf[4];
#pragma unroll
  for (int c = 0; c < 4; c++)
    qf[c] = frag64(smem, w * 32 + l31, c * 2 + hi);

  bf16x8 kones;
#pragma unroll
  for (int j = 0; j < 8; j++) kones[j] = (__bf16)1.0f;

  f32x16 o0 = {}, o1 = {}, o4 = {};

  for (int kt = 0; kt < 8; kt++) {
    const int s0 = kt * 128;
    __syncthreads();  // hoist (kt=0) / prev-tile reads complete
    stage64(Kg + (size_t)s0 * 4096, 4096, KsLo, w, lane);
    stage64(Kg + (size_t)(s0 + 64) * 4096, 4096, KsHi, w, lane);
    stage64(Vg + s0, 1024, VsLo, w, lane);
    stage64(Vg + s0 + 64, 1024, VsHi, w, lane);
    asm volatile("s_waitcnt vmcnt(0)" ::: "memory");
    __syncthreads();

    // 4 sub-tiles of 32 keys each: QK^T -> in-register P -> PV.
#pragma unroll
    for (int kb = 0; kb < 4; kb++) {
      const __hip_bfloat16* Ksb = (kb < 2) ? KsLo : KsHi;
      const __hip_bfloat16* Vsb = (kb < 2) ? VsLo : VsHi;
      const int lr = (kb & 1) * 32;       // local K row base within 64-block
      const int vc = (kb & 1) * 4;        // V chunk base within 64-wide half

      f32x16 sc = {};
      __builtin_amdgcn_s_setprio(1);
#pragma unroll
      for (int c = 0; c < 4; c++)
        sc = mfma32(frag64(Ksb, lr + l31, c * 2 + hi), qf[c], sc);
      __builtin_amdgcn_s_setprio(0);

      bf16x8 pfA, pfB;
#pragma unroll
      for (int hc = 0; hc < 2; hc++) {
        unsigned au0 = pkbf(exp2f(sc[8 * hc + 0]), exp2f(sc[8 * hc + 1]));
        unsigned au1 = pkbf(exp2f(sc[8 * hc + 2]), exp2f(sc[8 * hc + 3]));
        unsigned bu0 = pkbf(exp2f(sc[8 * hc + 4]), exp2f(sc[8 * hc + 5]));
        unsigned bu1 = pkbf(exp2f(sc[8 * hc + 6]), exp2f(sc[8 * hc + 7]));
        asm volatile("v_permlane32_swap_b32 %0, %1" : "+v"(au0), "+v"(bu0));
        asm volatile("v_permlane32_swap_b32 %0, %1" : "+v"(au1), "+v"(bu1));
        union { unsigned u[4]; bf16x8 v; } f;
        f.u[0] = au0; f.u[1] = au1; f.u[2] = bu0; f.u[3] = bu1;
        if (hc == 0) pfA = f.v; else pfB = f.v;
      }

      __builtin_amdgcn_s_setprio(1);
      o0 = mfma32(pfA, frag64(Vsb, l31, vc + 0 + hi), o0);
      o1 = mfma32(pfA, frag64(Vsb, 32 + l31, vc + 0 + hi), o1);
      o4 = mfma32(pfA, kones, o4);
      o0 = mfma32(pfB, frag64(Vsb, l31, vc + 2 + hi), o0);
      o1 = mfma32(pfB, frag64(Vsb, 32 + l31, vc + 2 + hi), o1);
      o4 = mfma32(pfB, kones, o4);
      __builtin_amdgcn_s_setprio(0);
    }
  }

  // Epilogue: C[q][d] rows q=(reg&3)+8*(reg>>2)+4*hi (+w*32), col d=l31(+32).
#pragma unroll
  for (int reg = 0; reg < 16; reg++) {
    const int qr = (reg & 3) + 8 * (reg >> 2) + 4 * hi;
    const float invl = 1.f / o4[reg];
    const size_t rowoff =
        ((size_t)b * 1024 + q0 + w * 32 + qr) * 4096 + h * 64;
    ctx[rowoff + l31] = __float2bfloat16(o0[reg] * invl);
    ctx[rowoff + 32 + l31] = __float2bfloat16(o1[reg] * invl);
    if (l31 == 0)
      lden[(size_t)bh * 1024 + q0 + w * 32 + qr] = log2f(o4[reg]);
  }
}

// ---------------- probsum: attn_sum[b,q,k] = sum_h 2^(s' - lden_h) ----------------
// k-tile 32, 1024 blocks; 2-phase double-buffered h-loop (stage h+1 before
// compute h). LDS 40KB -> 4 blocks/CU. exp-fold: lden subtracted inside exp2.
__global__ __launch_bounds__(256, 4) void probsum(
    const __hip_bfloat16* __restrict__ Qp, const __hip_bfloat16* __restrict__ Kp,
    const float* __restrict__ lden, float* __restrict__ outA) {
  const int lin = blockIdx.x;
  const int nw = (lin & 7) * 128 + (lin >> 3);  // XCD-chunked
  const int k0 = (nw & 31) * 32, q0 = ((nw >> 5) & 15) * 64, b = nw >> 9;
  __shared__ __hip_bfloat16 Qs[2][64 * 64];
  __shared__ __hip_bfloat16 Ks[2][32 * 64];
  __shared__ float Ls[64 * 64];  // [h][q]
  const int tid = threadIdx.x, lane = tid & 63, w = tid >> 6;
  const int l15 = lane & 15, l16 = lane >> 4;

  for (int i = tid; i < 4096; i += 256) {
    int h = i >> 6, qq = i & 63;
    Ls[h * 64 + qq] = lden[(size_t)(b * 64 + h) * 1024 + q0 + qq];
  }

  auto STG = [&](int buf, int h) {
    stage64(Qp + ((size_t)b * 1024 + q0) * 4096 + h * 64, 4096, Qs[buf], w, lane);
    stage32(Kp + ((size_t)b * 1024 + k0) * 4096 + h * 64, 4096, Ks[buf], w, lane);
  };

  f32x4 acc[2] = {};
  const int qrow = w * 16 + l16 * 4;

  STG(0, 0);
  asm volatile("s_waitcnt vmcnt(0)" ::: "memory");
  __syncthreads();
  int cur = 0;
  for (int h = 0; h < 64; h++) {
    if (h + 1 < 64) STG(cur ^ 1, h + 1);
    f32x4 sc[2] = {};
    __builtin_amdgcn_s_setprio(1);
#pragma unroll
    for (int ks = 0; ks < 2; ks++) {
      const int kg = ks * 4 + l16;
      bf16x8 aq = frag64(Qs[cur], w * 16 + l15, kg);
#pragma unroll
      for (int ni = 0; ni < 2; ni++)
        sc[ni] = mfma16(aq, frag64(Ks[cur], ni * 16 + l15, kg), sc[ni]);
    }
    __builtin_amdgcn_s_setprio(0);
    float nl[4];
#pragma unroll
    for (int rg = 0; rg < 4; rg++) nl[rg] = Ls[h * 64 + qrow + rg];
#pragma unroll
    for (int ni = 0; ni < 2; ni++)
#pragma unroll
      for (int rg = 0; rg < 4; rg++)
        acc[ni][rg] += exp2f(sc[ni][rg] - nl[rg]);
    asm volatile("s_waitcnt vmcnt(0)" ::: "memory");
    __syncthreads();
    cur ^= 1;
  }
  float* og = outA + ((size_t)b * 1024 + q0 + qrow) * 1024 + k0;
#pragma unroll
  for (int ni = 0; ni < 2; ni++)
#pragma unroll
    for (int rg = 0; rg < 4; rg++)
      og[(size_t)rg * 1024 + ni * 16 + l15] = acc[ni][rg];
}

// ---------------- host ----------------
extern "C" void kernel_launch(void* const* d_in, const int* in_sizes, int n_in,
                              void* d_out, int out_size, void* d_ws, size_t ws_size,
                              hipStream_t stream) {
  const float* q = (const float*)d_in[0];
  const float* k = (const float*)d_in[1];
  const float* v = (const float*)d_in[2];
  const float* Wq = (const float*)d_in[4];
  const float* bq = (const float*)d_in[5];
  const float* Wk = (const float*)d_in[6];
  const float* bk = (const float*)d_in[7];
  const float* Wv = (const float*)d_in[8];
  const float* bv = (const float*)d_in[9];
  const float* Wf = (const float*)d_in[10];
  const float* bfv = (const float*)d_in[11];
  float* out = (float*)d_out;
  float* attn_sum = out + (size_t)2048 * 512;

  char* ws = (char*)d_ws;
  auto alloc = [&](size_t bytes) {
    char* p = ws;
    ws += (bytes + 255) & ~(size_t)255;
    return p;
  };
  __hip_bfloat16* qb = (__hip_bfloat16*)alloc((size_t)2048 * 512 * 2);
  __hip_bfloat16* kb = (__hip_bfloat16*)alloc((size_t)2048 * 512 * 2);
  __hip_bfloat16* vb = (__hip_bfloat16*)alloc((size_t)2048 * 512 * 2);
  __hip_bfloat16* Wqt = (__hip_bfloat16*)alloc((size_t)4096 * 512 * 2);
  __hip_bfloat16* Wkt = (__hip_bfloat16*)alloc((size_t)4096 * 512 * 2);
  __hip_bfloat16* Wvt = (__hip_bfloat16*)alloc((size_t)4096 * 512 * 2);
  __hip_bfloat16* Wft = (__hip_bfloat16*)alloc((size_t)512 * 4096 * 2);
  __hip_bfloat16* Qp = (__hip_bfloat16*)alloc((size_t)2048 * 4096 * 2);
  __hip_bfloat16* Kp = (__hip_bfloat16*)alloc((size_t)2048 * 4096 * 2);
  __hip_bfloat16* Vt = (__hip_bfloat16*)alloc((size_t)2048 * 4096 * 2);
  __hip_bfloat16* ctx = (__hip_bfloat16*)alloc((size_t)2048 * 4096 * 2);
  float* lden = (float*)alloc((size_t)128 * 1024 * 4);
  // Split-K partials (4 x 2048 x 512 f32 = 16.8MB) reuse the dead qb..Wvt
  // region (18.9MB, all dead after the QKV GEMM).
  float* partial = (float*)qb;

  cast3_kernel<<<3072, 256, 0, stream>>>(q, k, v, qb, kb, vb);
  transpose4<<<dim3(128, 16, 4), dim3(32, 8), 0, stream>>>(Wq, Wk, Wv, Wf, Wqt, Wkt,
                                                           Wvt, Wft);
  GemmArgs gq{qb, Wqt, bq, Qp, 0, SC2};   // Q pre-scaled by SC2
  GemmArgs gk{kb, Wkt, bk, Kp, 0, 1.0f};
  GemmArgs gv{vb, Wvt, bv, Vt, 1, 1.0f};
  gemm_bf16<4, 4, 1><<<dim3(32, 16, 3), 256, 0, stream>>>(gq, gk, gv, 4096, 512);

  attn_flash<<<1024, 256, 0, stream>>>(Qp, Kp, Vt, ctx, lden);
  probsum<<<1024, 256, 0, stream>>>(Qp, Kp, lden, attn_sum);

  GemmArgs gf{ctx, Wft, bfv, partial, 3, 1.0f};
  gemm_bf16<2, 2, 4><<<dim3(8, 32, 4), 256, 0, stream>>>(gf, gf, gf, 512, 4096);
  reduce4_bias<<<1024, 256, 0, stream>>>(partial, bfv, out);
}

// Round 17
// 189.012 us; speedup vs baseline: 1.0127x; 1.0084x over previous
//
#include <hip/hip_runtime.h>
#include <hip/hip_bf16.h>

// MultiHeadAttention: B=2,S=1024,IN=512,P=4096,H=64,SZ=64
// cast -> transpose -> fused QKV GEMM (single-buffered; Q pre-scaled by SC2) ->
// flash attn (8-wave 32x32 MFMA, QBLK=256, KVBLK=128, Q-frags in regs, P in
// registers via permlane32_swap, ones-column rowsum) -> probsum (dbuf h-loop)
// -> split-K final GEMM. mask all-False -> ignored.
// MEASURED NOTES:
//  - GEMM dbuf (R5): 2x SLOWER. probsum dbuf (R9): +40%. attn LDS-dbuf (R10):
//    regressed; reg-prefetch (R12): spill; dbuf-in-deadQ (R15): RACE + void
//    (__syncthreads drains vmcnt). DO NOT RETRY cross-barrier prefetch.
//  - attn R9/R11/R14/R16 all 68.3-69.5us across 4 structures (DS-ops, conflicts,
//    barrier count all varied): bound is wait-dominated at ~2-3 waves/SIMD.
//    This round: 8-wave QBLK=256 -> 16 waves/CU AND half the K/V L2 restaging.

typedef __bf16 bf16x8 __attribute__((ext_vector_type(8)));
typedef float f32x4 __attribute__((ext_vector_type(4)));
typedef float f32x16 __attribute__((ext_vector_type(16)));

#define DEV __device__ __forceinline__

// 0.125 * log2(e): softmax in base-2 (v_exp_f32 computes 2^x).
// Q projection is pre-scaled by this, so QK^T emits s' = s*SC2 directly.
#define SC2 0.18033688011112042f

DEV f32x4 mfma16(bf16x8 a, bf16x8 b, f32x4 c) {
  return __builtin_amdgcn_mfma_f32_16x16x32_bf16(a, b, c, 0, 0, 0);
}

DEV f32x16 mfma32(bf16x8 a, bf16x8 b, f32x16 c) {
  return __builtin_amdgcn_mfma_f32_32x32x16_bf16(a, b, c, 0, 0, 0);
}

DEV void gload_lds16(const void* g, void* l) {
  __builtin_amdgcn_global_load_lds(
      (const __attribute__((address_space(1))) unsigned int*)g,
      (__attribute__((address_space(3))) unsigned int*)l, 16, 0, 0);
}

DEV unsigned short bf16bits(float f) {
  __hip_bfloat16 h = __float2bfloat16(f);
  return *reinterpret_cast<unsigned short*>(&h);
}

DEV unsigned pkbf(float lo, float hi) {
  return (unsigned)bf16bits(lo) | ((unsigned)bf16bits(hi) << 16);
}

// Stage a 64x64 bf16 tile into LDS with T2 XOR swizzle (both-sides rule #21):
// logical element (r,k) lives at LDS elem r*64 + ((k/8)^(r&7))*8.
// 4-wave version (waves 0..3, 2 gloads each).
DEV void stage64(const __hip_bfloat16* src, size_t srcStride, __hip_bfloat16* dst,
                 int w, int lane) {
#pragma unroll
  for (int i = 0; i < 2; i++) {
    int r = i * 32 + w * 8 + (lane >> 3);
    int kg = (lane & 7) ^ (r & 7);
    gload_lds16(src + (size_t)r * srcStride + kg * 8, dst + (i * 32 + w * 8) * 64);
  }
}

// Stage a 32x64 tile (4 waves, 1 gload each).
DEV void stage32(const __hip_bfloat16* src, size_t srcStride, __hip_bfloat16* dst,
                 int w, int lane) {
  int r = w * 8 + (lane >> 3);
  int kg = (lane & 7) ^ (r & 7);
  gload_lds16(src + (size_t)r * srcStride + kg * 8, dst + (w * 8) * 64);
}

// 8-wave: 64 rows, 1 gload per thread.
DEV void stage64_8w(const __hip_bfloat16* src, size_t srcStride,
                    __hip_bfloat16* dst, int w, int lane) {
  int r = w * 8 + (lane >> 3);
  int kg = (lane & 7) ^ (r & 7);
  gload_lds16(src + (size_t)r * srcStride + kg * 8, dst + (w * 8) * 64);
}

// 8-wave: 256 rows, 4 gloads per thread.
DEV void stage256_8w(const __hip_bfloat16* src, size_t srcStride,
                     __hip_bfloat16* dst, int w, int lane) {
#pragma unroll
  for (int i = 0; i < 4; i++) {
    int r = i * 64 + w * 8 + (lane >> 3);
    int kg = (lane & 7) ^ (r & 7);
    gload_lds16(src + (size_t)r * srcStride + kg * 8, dst + (i * 64 + w * 8) * 64);
  }
}

// Read swizzled fragment: logical (row, kgroup kg) -> bf16x8 (16B-aligned).
DEV bf16x8 frag64(const __hip_bfloat16* tile, int row, int kg) {
  return *reinterpret_cast<const bf16x8*>(tile + row * 64 + ((kg ^ (row & 7)) * 8));
}

// ---------------- cast f32 -> bf16, all three tensors in one launch ----------------
__global__ void cast3_kernel(const float* __restrict__ q, const float* __restrict__ k,
                             const float* __restrict__ v, __hip_bfloat16* __restrict__ qb,
                             __hip_bfloat16* __restrict__ kb,
                             __hip_bfloat16* __restrict__ vb) {
  int i = blockIdx.x * blockDim.x + threadIdx.x;  // [0, 3*2^18)
  int which = i >> 18, off = i & 0x3FFFF;
  const float* src = which == 0 ? q : which == 1 ? k : v;
  __hip_bfloat16* dst = which == 0 ? qb : which == 1 ? kb : vb;
  float4 f = reinterpret_cast<const float4*>(src)[off];
  union { unsigned short u[4]; uint2 v2; } pk;
  pk.u[0] = bf16bits(f.x); pk.u[1] = bf16bits(f.y);
  pk.u[2] = bf16bits(f.z); pk.u[3] = bf16bits(f.w);
  reinterpret_cast<uint2*>(dst)[off] = pk.v2;
}

// ---------------- transpose + cast, all four weights in one launch ----------------
__global__ void transpose4(const float* __restrict__ Wq, const float* __restrict__ Wk,
                           const float* __restrict__ Wv, const float* __restrict__ Wf,
                           __hip_bfloat16* __restrict__ Wqt, __hip_bfloat16* __restrict__ Wkt,
                           __hip_bfloat16* __restrict__ Wvt, __hip_bfloat16* __restrict__ Wft) {
  __shared__ float t[32][33];
  const int z = blockIdx.z;
  const float* W = z == 0 ? Wq : z == 1 ? Wk : z == 2 ? Wv : Wf;
  __hip_bfloat16* Wt = z == 0 ? Wqt : z == 1 ? Wkt : z == 2 ? Wvt : Wft;
  int K, N, n0, k0;
  if (z < 3) { K = 512; N = 4096; n0 = blockIdx.x * 32; k0 = blockIdx.y * 32; }
  else       { K = 4096; N = 512; n0 = blockIdx.y * 32; k0 = blockIdx.x * 32; }
  int tx = threadIdx.x, ty = threadIdx.y;
#pragma unroll
  for (int i = 0; i < 4; i++)
    t[ty + i * 8][tx] = W[(size_t)(k0 + ty + i * 8) * N + n0 + tx];
  __syncthreads();
#pragma unroll
  for (int i = 0; i < 4; i++)
    Wt[(size_t)(n0 + ty + i * 8) * K + k0 + tx] = __float2bfloat16(t[tx][ty + i * 8]);
}

// ---------------- GEMM: C[M,N] = A[M,K] @ Bt[N,K]^T (+ bias) ----------------
// mode 0: bf16 natural, value = (acc+bias)*scale
// mode 1: bf16 transposed per batch (Vt[b][n][s]), value = acc+bias
// mode 3: f32 partial (split-K chunk blockIdx.z), no bias
struct GemmArgs {
  const __hip_bfloat16* A;
  const __hip_bfloat16* Bt;
  const float* bias;
  void* C;
  int mode;
  float scale;
};

template <int MI, int NI, int SPLITK>
__global__ __launch_bounds__(256, 2) void gemm_bf16(GemmArgs g0, GemmArgs g1,
                                                    GemmArgs g2, int Ndim, int Kdim) {
  const GemmArgs& g =
      (SPLITK > 1) ? g0 : (blockIdx.z == 0 ? g0 : blockIdx.z == 1 ? g1 : g2);
  constexpr int BM = 32 * MI, BN = 32 * NI;
  __shared__ __hip_bfloat16 As[BM * 64];
  __shared__ __hip_bfloat16 Bs[BN * 64];
  const int tid = threadIdx.x;
  const int lane = tid & 63, w = tid >> 6;
  const int wr = w >> 1, wc = w & 1;
  const int row0 = blockIdx.y * BM, col0 = blockIdx.x * BN;
  const int l15 = lane & 15, l16 = lane >> 4;

  const int kchunk = Kdim / SPLITK;
  const int kbeg = (SPLITK > 1) ? blockIdx.z * kchunk : 0;

  f32x4 acc[MI][NI] = {};

  const int sr8 = w * 8 + (lane >> 3);
  const int sslot = lane & 7;

  for (int t = 0; t < kchunk / 64; ++t) {
    const int k0 = kbeg + t * 64;
    __syncthreads();
#pragma unroll
    for (int i = 0; i < MI; i++) {
      int r = i * 32 + sr8;
      int kg = sslot ^ (r & 7);
      gload_lds16(g.A + (size_t)(row0 + r) * Kdim + k0 + kg * 8,
                  As + (i * 32 + w * 8) * 64);
    }
#pragma unroll
    for (int i = 0; i < NI; i++) {
      int r = i * 32 + sr8;
      int kg = sslot ^ (r & 7);
      gload_lds16(g.Bt + (size_t)(col0 + r) * Kdim + k0 + kg * 8,
                  Bs + (i * 32 + w * 8) * 64);
    }
    asm volatile("s_waitcnt vmcnt(0)" ::: "memory");
    __syncthreads();
#pragma unroll
    for (int ks = 0; ks < 2; ks++) {
      const int kg = ks * 4 + l16;
      bf16x8 af[MI], bfr[NI];
#pragma unroll
      for (int mi = 0; mi < MI; mi++)
        af[mi] = frag64(As, wr * (16 * MI) + mi * 16 + l15, kg);
#pragma unroll
      for (int ni = 0; ni < NI; ni++)
        bfr[ni] = frag64(Bs, wc * (16 * NI) + ni * 16 + l15, kg);
      __builtin_amdgcn_s_setprio(1);
#pragma unroll
      for (int mi = 0; mi < MI; mi++)
#pragma unroll
        for (int ni = 0; ni < NI; ni++)
          acc[mi][ni] = mfma16(af[mi], bfr[ni], acc[mi][ni]);
      __builtin_amdgcn_s_setprio(0);
    }
  }

#pragma unroll
  for (int mi = 0; mi < MI; mi++) {
    const int rbase = row0 + wr * (16 * MI) + mi * 16 + l16 * 4;
#pragma unroll
    for (int ni = 0; ni < NI; ni++) {
      const int col = col0 + wc * (16 * NI) + ni * 16 + l15;
      if (g.mode == 0) {
        const float bv = g.bias[col];
#pragma unroll
        for (int rg = 0; rg < 4; rg++)
          ((__hip_bfloat16*)g.C)[(size_t)(rbase + rg) * Ndim + col] =
              __float2bfloat16((acc[mi][ni][rg] + bv) * g.scale);
      } else if (g.mode == 1) {
        const float bv = g.bias[col];
        const int b = rbase >> 10, s = rbase & 1023;
        union { unsigned short u[4]; uint2 v2; } pk;
#pragma unroll
        for (int rg = 0; rg < 4; rg++) pk.u[rg] = bf16bits(acc[mi][ni][rg] + bv);
        *reinterpret_cast<uint2*>((__hip_bfloat16*)g.C +
                                  ((size_t)b * 4096 + col) * 1024 + s) = pk.v2;
      } else {  // mode 3: split-K f32 partial, no bias
        float* base = (float*)g.C +
                      (size_t)blockIdx.z * (size_t)(gridDim.y * BM) * Ndim;
#pragma unroll
        for (int rg = 0; rg < 4; rg++)
          base[(size_t)(rbase + rg) * Ndim + col] = acc[mi][ni][rg];
      }
    }
  }
}

// ---------------- split-K reduce: out = sum_z partial[z] + bias ----------------
__global__ void reduce4_bias(const float* __restrict__ part,
                             const float* __restrict__ bias,
                             float* __restrict__ out) {
  int i = blockIdx.x * blockDim.x + threadIdx.x;  // 262144 float4 groups
  const size_t S4 = (size_t)2048 * 512 / 4;
  float4 a = reinterpret_cast<const float4*>(part)[i];
  float4 b = reinterpret_cast<const float4*>(part)[i + S4];
  float4 c = reinterpret_cast<const float4*>(part)[i + 2 * S4];
  float4 d = reinterpret_cast<const float4*>(part)[i + 3 * S4];
  float4 bv = reinterpret_cast<const float4*>(bias)[i & 127];
  float4 r;
  r.x = a.x + b.x + c.x + d.x + bv.x;
  r.y = a.y + b.y + c.y + d.y + bv.y;
  r.z = a.z + b.z + c.z + d.z + bv.z;
  r.w = a.w + b.w + c.w + d.w + bv.w;
  reinterpret_cast<float4*>(out)[i] = r;
}

// ---------------- flash attention: 8-wave 32x32, reg-P, QBLK=256, KVBLK=128 ----------------
// Qp pre-scaled by SC2 -> QK^T yields s', P = 2^s'.
// Swapped QK^T: mfma32(A=K, B=Q) -> C[k][q]; in-register P via exp2 -> cvt_pk
// -> v_permlane32_swap (layout verified R14/R16). 8 waves x 32 q-rows = 256 q.
// Grid 512 blocks = 2/CU; LDS 64KB -> exactly 2 blocks/CU = 16 waves (50%).
// K/V restaged 4x per bh (was 8x): L2 traffic halves.
// Sync skeleton: {barrier; stage; vmcnt(0); barrier; compute} x 8 (proven).
__global__ __launch_bounds__(512, 4) void attn_flash(
    const __hip_bfloat16* __restrict__ Qp, const __hip_bfloat16* __restrict__ Kp,
    const __hip_bfloat16* __restrict__ Vt, __hip_bfloat16* __restrict__ ctx,
    float* __restrict__ lden) {
  const int lin = blockIdx.x;                  // 512 blocks
  const int nw = (lin & 7) * 64 + (lin >> 3);  // XCD-chunked: 4 consecutive = same bh
  const int bh = nw >> 2, q0 = (nw & 3) * 256;
  const int b = bh >> 6, h = bh & 63;
  // smem elems: [0,16384) Qs 256x64; [16384,20480) KsLo; [20480,24576) KsHi;
  //             [24576,28672) VsLo; [28672,32768) VsHi.  Total 64KB.
  __shared__ __hip_bfloat16 smem[32768];
  __hip_bfloat16* Qs = smem;
  __hip_bfloat16* KsLo = smem + 16384;
  __hip_bfloat16* KsHi = smem + 20480;
  __hip_bfloat16* VsLo = smem + 24576;
  __hip_bfloat16* VsHi = smem + 28672;
  const int tid = threadIdx.x, lane = tid & 63, w = tid >> 6;  // w 0..7
  const int l31 = lane & 31, hi = lane >> 5;

  const __hip_bfloat16* Qg = Qp + ((size_t)b * 1024 + q0) * 4096 + h * 64;
  const __hip_bfloat16* Kg = Kp + (size_t)b * 1024 * 4096 + h * 64;
  const __hip_bfloat16* Vg = Vt + ((size_t)b * 4096 + h * 64) * 1024;

  // Prologue: stage Q (256 rows), drain, hoist to regs.
  stage256_8w(Qg, 4096, Qs, w, lane);
  asm volatile("s_waitcnt vmcnt(0)" ::: "memory");
  __syncthreads();

  bf16x8 qf[4];
#pragma unroll
  for (int c = 0; c < 4; c++)
    qf[c] = frag64(Qs, w * 32 + l31, c * 2 + hi);

  bf16x8 kones;
#pragma unroll
  for (int j = 0; j < 8; j++) kones[j] = (__bf16)1.0f;

  f32x16 o0 = {}, o1 = {}, o4 = {};

  for (int kt = 0; kt < 8; kt++) {
    const int s0 = kt * 128;
    __syncthreads();  // hoist (kt=0) / prev-tile reads complete
    stage64_8w(Kg + (size_t)s0 * 4096, 4096, KsLo, w, lane);
    stage64_8w(Kg + (size_t)(s0 + 64) * 4096, 4096, KsHi, w, lane);
    stage64_8w(Vg + s0, 1024, VsLo, w, lane);
    stage64_8w(Vg + s0 + 64, 1024, VsHi, w, lane);
    asm volatile("s_waitcnt vmcnt(0)" ::: "memory");
    __syncthreads();

    // 4 sub-tiles of 32 keys each: QK^T -> in-register P -> PV.
#pragma unroll
    for (int kb = 0; kb < 4; kb++) {
      const __hip_bfloat16* Ksb = (kb < 2) ? KsLo : KsHi;
      const __hip_bfloat16* Vsb = (kb < 2) ? VsLo : VsHi;
      const int lr = (kb & 1) * 32;       // local K row base within 64-block
      const int vc = (kb & 1) * 4;        // V chunk base within 64-wide half

      f32x16 sc = {};
      __builtin_amdgcn_s_setprio(1);
#pragma unroll
      for (int c = 0; c < 4; c++)
        sc = mfma32(frag64(Ksb, lr + l31, c * 2 + hi), qf[c], sc);
      __builtin_amdgcn_s_setprio(0);

      bf16x8 pfA, pfB;
#pragma unroll
      for (int hc = 0; hc < 2; hc++) {
        unsigned au0 = pkbf(exp2f(sc[8 * hc + 0]), exp2f(sc[8 * hc + 1]));
        unsigned au1 = pkbf(exp2f(sc[8 * hc + 2]), exp2f(sc[8 * hc + 3]));
        unsigned bu0 = pkbf(exp2f(sc[8 * hc + 4]), exp2f(sc[8 * hc + 5]));
        unsigned bu1 = pkbf(exp2f(sc[8 * hc + 6]), exp2f(sc[8 * hc + 7]));
        asm volatile("v_permlane32_swap_b32 %0, %1" : "+v"(au0), "+v"(bu0));
        asm volatile("v_permlane32_swap_b32 %0, %1" : "+v"(au1), "+v"(bu1));
        union { unsigned u[4]; bf16x8 v; } f;
        f.u[0] = au0; f.u[1] = au1; f.u[2] = bu0; f.u[3] = bu1;
        if (hc == 0) pfA = f.v; else pfB = f.v;
      }

      __builtin_amdgcn_s_setprio(1);
      o0 = mfma32(pfA, frag64(Vsb, l31, vc + 0 + hi), o0);
      o1 = mfma32(pfA, frag64(Vsb, 32 + l31, vc + 0 + hi), o1);
      o4 = mfma32(pfA, kones, o4);
      o0 = mfma32(pfB, frag64(Vsb, l31, vc + 2 + hi), o0);
      o1 = mfma32(pfB, frag64(Vsb, 32 + l31, vc + 2 + hi), o1);
      o4 = mfma32(pfB, kones, o4);
      __builtin_amdgcn_s_setprio(0);
    }
  }

  // Epilogue: C[q][d] rows q=(reg&3)+8*(reg>>2)+4*hi (+w*32), col d=l31(+32).
#pragma unroll
  for (int reg = 0; reg < 16; reg++) {
    const int qr = (reg & 3) + 8 * (reg >> 2) + 4 * hi;
    const float invl = 1.f / o4[reg];
    const size_t rowoff =
        ((size_t)b * 1024 + q0 + w * 32 + qr) * 4096 + h * 64;
    ctx[rowoff + l31] = __float2bfloat16(o0[reg] * invl);
    ctx[rowoff + 32 + l31] = __float2bfloat16(o1[reg] * invl);
    if (l31 == 0)
      lden[(size_t)bh * 1024 + q0 + w * 32 + qr] = log2f(o4[reg]);
  }
}

// ---------------- probsum: attn_sum[b,q,k] = sum_h 2^(s' - lden_h) ----------------
// k-tile 32, 1024 blocks; 2-phase double-buffered h-loop (stage h+1 before
// compute h). LDS 40KB -> 4 blocks/CU. exp-fold: lden subtracted inside exp2.
__global__ __launch_bounds__(256, 4) void probsum(
    const __hip_bfloat16* __restrict__ Qp, const __hip_bfloat16* __restrict__ Kp,
    const float* __restrict__ lden, float* __restrict__ outA) {
  const int lin = blockIdx.x;
  const int nw = (lin & 7) * 128 + (lin >> 3);  // XCD-chunked
  const int k0 = (nw & 31) * 32, q0 = ((nw >> 5) & 15) * 64, b = nw >> 9;
  __shared__ __hip_bfloat16 Qs[2][64 * 64];
  __shared__ __hip_bfloat16 Ks[2][32 * 64];
  __shared__ float Ls[64 * 64];  // [h][q]
  const int tid = threadIdx.x, lane = tid & 63, w = tid >> 6;
  const int l15 = lane & 15, l16 = lane >> 4;

  for (int i = tid; i < 4096; i += 256) {
    int h = i >> 6, qq = i & 63;
    Ls[h * 64 + qq] = lden[(size_t)(b * 64 + h) * 1024 + q0 + qq];
  }

  auto STG = [&](int buf, int h) {
    stage64(Qp + ((size_t)b * 1024 + q0) * 4096 + h * 64, 4096, Qs[buf], w, lane);
    stage32(Kp + ((size_t)b * 1024 + k0) * 4096 + h * 64, 4096, Ks[buf], w, lane);
  };

  f32x4 acc[2] = {};
  const int qrow = w * 16 + l16 * 4;

  STG(0, 0);
  asm volatile("s_waitcnt vmcnt(0)" ::: "memory");
  __syncthreads();
  int cur = 0;
  for (int h = 0; h < 64; h++) {
    if (h + 1 < 64) STG(cur ^ 1, h + 1);
    f32x4 sc[2] = {};
    __builtin_amdgcn_s_setprio(1);
#pragma unroll
    for (int ks = 0; ks < 2; ks++) {
      const int kg = ks * 4 + l16;
      bf16x8 aq = frag64(Qs[cur], w * 16 + l15, kg);
#pragma unroll
      for (int ni = 0; ni < 2; ni++)
        sc[ni] = mfma16(aq, frag64(Ks[cur], ni * 16 + l15, kg), sc[ni]);
    }
    __builtin_amdgcn_s_setprio(0);
    float nl[4];
#pragma unroll
    for (int rg = 0; rg < 4; rg++) nl[rg] = Ls[h * 64 + qrow + rg];
#pragma unroll
    for (int ni = 0; ni < 2; ni++)
#pragma unroll
      for (int rg = 0; rg < 4; rg++)
        acc[ni][rg] += exp2f(sc[ni][rg] - nl[rg]);
    asm volatile("s_waitcnt vmcnt(0)" ::: "memory");
    __syncthreads();
    cur ^= 1;
  }
  float* og = outA + ((size_t)b * 1024 + q0 + qrow) * 1024 + k0;
#pragma unroll
  for (int ni = 0; ni < 2; ni++)
#pragma unroll
    for (int rg = 0; rg < 4; rg++)
      og[(size_t)rg * 1024 + ni * 16 + l15] = acc[ni][rg];
}

// ---------------- host ----------------
extern "C" void kernel_launch(void* const* d_in, const int* in_sizes, int n_in,
                              void* d_out, int out_size, void* d_ws, size_t ws_size,
                              hipStream_t stream) {
  const float* q = (const float*)d_in[0];
  const float* k = (const float*)d_in[1];
  const float* v = (const float*)d_in[2];
  const float* Wq = (const float*)d_in[4];
  const float* bq = (const float*)d_in[5];
  const float* Wk = (const float*)d_in[6];
  const float* bk = (const float*)d_in[7];
  const float* Wv = (const float*)d_in[8];
  const float* bv = (const float*)d_in[9];
  const float* Wf = (const float*)d_in[10];
  const float* bfv = (const float*)d_in[11];
  float* out = (float*)d_out;
  float* attn_sum = out + (size_t)2048 * 512;

  char* ws = (char*)d_ws;
  auto alloc = [&](size_t bytes) {
    char* p = ws;
    ws += (bytes + 255) & ~(size_t)255;
    return p;
  };
  __hip_bfloat16* qb = (__hip_bfloat16*)alloc((size_t)2048 * 512 * 2);
  __hip_bfloat16* kb = (__hip_bfloat16*)alloc((size_t)2048 * 512 * 2);
  __hip_bfloat16* vb = (__hip_bfloat16*)alloc((size_t)2048 * 512 * 2);
  __hip_bfloat16* Wqt = (__hip_bfloat16*)alloc((size_t)4096 * 512 * 2);
  __hip_bfloat16* Wkt = (__hip_bfloat16*)alloc((size_t)4096 * 512 * 2);
  __hip_bfloat16* Wvt = (__hip_bfloat16*)alloc((size_t)4096 * 512 * 2);
  __hip_bfloat16* Wft = (__hip_bfloat16*)alloc((size_t)512 * 4096 * 2);
  __hip_bfloat16* Qp = (__hip_bfloat16*)alloc((size_t)2048 * 4096 * 2);
  __hip_bfloat16* Kp = (__hip_bfloat16*)alloc((size_t)2048 * 4096 * 2);
  __hip_bfloat16* Vt = (__hip_bfloat16*)alloc((size_t)2048 * 4096 * 2);
  __hip_bfloat16* ctx = (__hip_bfloat16*)alloc((size_t)2048 * 4096 * 2);
  float* lden = (float*)alloc((size_t)128 * 1024 * 4);
  // Split-K partials (4 x 2048 x 512 f32 = 16.8MB) reuse the dead qb..Wvt
  // region (18.9MB, all dead after the QKV GEMM).
  float* partial = (float*)qb;

  cast3_kernel<<<3072, 256, 0, stream>>>(q, k, v, qb, kb, vb);
  transpose4<<<dim3(128, 16, 4), dim3(32, 8), 0, stream>>>(Wq, Wk, Wv, Wf, Wqt, Wkt,
                                                           Wvt, Wft);
  GemmArgs gq{qb, Wqt, bq, Qp, 0, SC2};   // Q pre-scaled by SC2
  GemmArgs gk{kb, Wkt, bk, Kp, 0, 1.0f};
  GemmArgs gv{vb, Wvt, bv, Vt, 1, 1.0f};
  gemm_bf16<4, 4, 1><<<dim3(32, 16, 3), 256, 0, stream>>>(gq, gk, gv, 4096, 512);

  attn_flash<<<512, 512, 0, stream>>>(Qp, Kp, Vt, ctx, lden);
  probsum<<<1024, 256, 0, stream>>>(Qp, Kp, lden, attn_sum);

  GemmArgs gf{ctx, Wft, bfv, partial, 3, 1.0f};
  gemm_bf16<2, 2, 4><<<dim3(8, 32, 4), 256, 0, stream>>>(gf, gf, gf, 512, 4096);
  reduce4_bias<<<1024, 256, 0, stream>>>(partial, bfv, out);
}